// Round 6
// baseline (25132.777 us; speedup 1.0000x reference)
//
#include <hip/hip_runtime.h>

// Farthest point sampling, B=32, N=32768, npoint=4096.
// One block per batch; 1024 threads; each thread owns 32 points in registers.
// OUTPUT float32: [B*NPOINT] idx values, then [B*NPOINT*3] coords.
//
// Arithmetic hypothesis (R6): ref = XLA-compiled chain with LLVM-canonical
// contraction of ((0+dx^2)+dy^2)+dz^2:
//   inner: fadd(fmul(dx,dx), fmul(dy,dy)) -> fma(dx,dx, dy*dy)
//          (first operand fuses; dy^2 gets the separate rounding)
//   outer: -> fma(dz,dz, inner)
// so  d = fmaf(dz,dz, fmaf(dx,dx, dy*dy))
// contract(off) pins everything else; explicit fmaf stays fused.

#define BATCH 32
#define NPTS  32768
#define NPOINT 4096
#define NT    1024
#define NPT   (NPTS / NT)   // 32 points per thread

__global__ __launch_bounds__(NT, 1) void fps_kernel(
    const float* __restrict__ xyz,   // [B, N, 3] float32
    float* __restrict__ out_idx,     // [B, NPOINT]
    float* __restrict__ out_xyz)     // [B, NPOINT, 3]
{
#pragma clang fp contract(off)
    const int b   = blockIdx.x;
    const int tid = threadIdx.x;
    const float* base = xyz + (size_t)b * NPTS * 3;

    float px[NPT], py[NPT], pz[NPT], dist[NPT];
#pragma unroll
    for (int i = 0; i < NPT; ++i) {
        const int g = i * NT + tid;
        px[i] = base[g * 3 + 0];
        py[i] = base[g * 3 + 1];
        pz[i] = base[g * 3 + 2];
        dist[i] = 1e10f;
    }

    __shared__ float s_c[3];
    __shared__ float s_val[16];
    __shared__ int   s_idx[16];
    __shared__ int   s_winner;

    int winner = 1;   // RAN=False seed

    for (int k = 0; k < NPOINT; ++k) {
        // Owner thread of current winner: publish centroid + emit outputs.
        if (tid == (winner & (NT - 1))) {
            const int slot = winner >> 10;   // winner / NT
            const float cx = px[slot], cy = py[slot], cz = pz[slot];
            s_c[0] = cx; s_c[1] = cy; s_c[2] = cz;
            out_idx[(size_t)b * NPOINT + k] = (float)winner;
            float* o = out_xyz + ((size_t)b * NPOINT + k) * 3;
            o[0] = cx; o[1] = cy; o[2] = cz;
        }
        __syncthreads();                         // barrier 1: centroid ready
        const float cx = s_c[0], cy = s_c[1], cz = s_c[2];

        // Local distance update + first-occurrence argmax over my 32 points.
        float best = -1.0f;
        int   bi   = 0x7fffffff;
#pragma unroll
        for (int i = 0; i < NPT; ++i) {
            const float dx = px[i] - cx;
            const float dy = py[i] - cy;
            const float dz = pz[i] - cz;
            // LLVM-canonical contracted chain (see header comment):
            const float d = fmaf(dz, dz, fmaf(dx, dx, dy * dy));
            const float nd = fminf(dist[i], d);
            dist[i] = nd;
            // ascending global index within thread -> strict > keeps first max
            if (nd > best) { best = nd; bi = i * NT + tid; }
        }

        // Wave (64-lane) butterfly argmax; ties -> smaller index.
#pragma unroll
        for (int off = 1; off < 64; off <<= 1) {
            const float ov = __shfl_xor(best, off, 64);
            const int   oi = __shfl_xor(bi,   off, 64);
            if (ov > best || (ov == best && oi < bi)) { best = ov; bi = oi; }
        }
        const int wv = tid >> 6;                 // wave id 0..15
        if ((tid & 63) == 0) { s_val[wv] = best; s_idx[wv] = bi; }
        __syncthreads();                         // barrier 2: wave partials ready

        if (tid < 64) {
            float v  = (tid < 16) ? s_val[tid] : -2.0f;
            int   ix = (tid < 16) ? s_idx[tid] : 0x7fffffff;
#pragma unroll
            for (int off = 1; off < 16; off <<= 1) {
                const float ov = __shfl_xor(v,  off, 64);
                const int   oi = __shfl_xor(ix, off, 64);
                if (ov > v || (ov == v && oi < ix)) { v = ov; ix = oi; }
            }
            if (tid == 0) s_winner = ix;
        }
        __syncthreads();                         // barrier 3: winner ready
        winner = s_winner;
    }
}

extern "C" void kernel_launch(void* const* d_in, const int* in_sizes, int n_in,
                              void* d_out, int out_size, void* d_ws, size_t ws_size,
                              hipStream_t stream) {
    const float* xyz = (const float*)d_in[0];
    float* out = (float*)d_out;
    float* out_idx = out;                              // B*NPOINT floats
    float* out_xyz = out + (size_t)BATCH * NPOINT;     // B*NPOINT*3 floats

    fps_kernel<<<BATCH, NT, 0, stream>>>(xyz, out_idx, out_xyz);
}

// Round 7
// 13363.866 us; speedup vs baseline: 1.8807x; 1.8807x over previous
//
#include <hip/hip_runtime.h>

// Farthest point sampling, B=32, N=32768, npoint=4096. PASSING arithmetic
// (R6): d = fmaf(dz,dz, fmaf(dx,dx, dy*dy)), contract(off), fminf chain,
// first-occurrence argmax. Output float32: [B*NPOINT] idx, [B*NPOINT*3] xyz.
//
// R7 perf fix: R6 had VGPR_Count=64 + 19MB/dispatch scratch writes because
// px[slot] (runtime slot) forced coord arrays to scratch (rule #20) and the
// 128-reg cap spilled the rest.
//  - centroid now read from GLOBAL by all threads (broadcast, L2-hot) ->
//    no runtime-indexed register array, owner branch + 1 barrier removed.
//  - pz lives in LDS (128KB dynamic, strided = bank-conflict-free b32);
//    px,py,dist stay in registers: live set ~117 regs < 128 cap -> no spill.

#define BATCH  32
#define NPTS   32768
#define NPOINT 4096
#define NT     1024
#define NPT    (NPTS / NT)   // 32 points per thread

#define SMEM_BYTES (NPTS * 4 + 64 + 64 + 16)

__global__ __launch_bounds__(NT, 1) void fps_kernel(
    const float* __restrict__ xyz,   // [B, N, 3] float32
    float* __restrict__ out_idx,     // [B, NPOINT]
    float* __restrict__ out_xyz)     // [B, NPOINT, 3]
{
#pragma clang fp contract(off)
    extern __shared__ char smem[];
    float* pz_lds = (float*)smem;                      // NPTS floats (128 KB)
    float* s_val  = (float*)(smem + NPTS * 4);         // 16 floats
    int*   s_idx  = (int*)  (smem + NPTS * 4 + 64);    // 16 ints
    int*   s_win  = (int*)  (smem + NPTS * 4 + 128);   // 1 int

    const int b   = blockIdx.x;
    const int tid = threadIdx.x;
    const float* base = xyz + (size_t)b * NPTS * 3;

    float px[NPT], py[NPT], dist[NPT];
#pragma unroll
    for (int i = 0; i < NPT; ++i) {
        const int g = i * NT + tid;
        px[i] = base[g * 3 + 0];
        py[i] = base[g * 3 + 1];
        pz_lds[g] = base[g * 3 + 2];
        dist[i] = 1e10f;
    }
    __syncthreads();                       // pz_lds ready

    int winner = 1;   // RAN=False seed

    for (int k = 0; k < NPOINT; ++k) {
        // Broadcast centroid from global (same addr across lanes -> 1 fetch).
        const float cx = base[winner * 3 + 0];
        const float cy = base[winner * 3 + 1];
        const float cz = base[winner * 3 + 2];
        if (tid == 0) {
            out_idx[(size_t)b * NPOINT + k] = (float)winner;
            float* o = out_xyz + ((size_t)b * NPOINT + k) * 3;
            o[0] = cx; o[1] = cy; o[2] = cz;
        }

        // Distance update + first-occurrence argmax, chunks of 8 to bound
        // pz temp pressure.
        float best = -1.0f;
        int   bi   = 0x7fffffff;
#pragma unroll
        for (int c = 0; c < NPT / 8; ++c) {
            float pzv[8];
#pragma unroll
            for (int j = 0; j < 8; ++j)
                pzv[j] = pz_lds[(c * 8 + j) * NT + tid];
#pragma unroll
            for (int j = 0; j < 8; ++j) {
                const int i = c * 8 + j;
                const float dx = px[i] - cx;
                const float dy = py[i] - cy;
                const float dz = pzv[j] - cz;
                const float d  = fmaf(dz, dz, fmaf(dx, dx, dy * dy));
                const float nd = fminf(dist[i], d);
                dist[i] = nd;
                if (nd > best) { best = nd; bi = i * NT + tid; }
            }
        }

        // Wave (64-lane) butterfly argmax; ties -> smaller index.
#pragma unroll
        for (int off = 1; off < 64; off <<= 1) {
            const float ov = __shfl_xor(best, off, 64);
            const int   oi = __shfl_xor(bi,   off, 64);
            if (ov > best || (ov == best && oi < bi)) { best = ov; bi = oi; }
        }
        const int wv = tid >> 6;           // wave id 0..15
        if ((tid & 63) == 0) { s_val[wv] = best; s_idx[wv] = bi; }
        __syncthreads();                   // barrier A: wave partials ready

        if (tid < 64) {
            float v  = (tid < 16) ? s_val[tid] : -2.0f;
            int   ix = (tid < 16) ? s_idx[tid] : 0x7fffffff;
#pragma unroll
            for (int off = 1; off < 16; off <<= 1) {
                const float ov = __shfl_xor(v,  off, 64);
                const int   oi = __shfl_xor(ix, off, 64);
                if (ov > v || (ov == v && oi < ix)) { v = ov; ix = oi; }
            }
            if (tid == 0) *s_win = ix;
        }
        __syncthreads();                   // barrier B: winner ready
        winner = *s_win;
    }
}

extern "C" void kernel_launch(void* const* d_in, const int* in_sizes, int n_in,
                              void* d_out, int out_size, void* d_ws, size_t ws_size,
                              hipStream_t stream) {
    const float* xyz = (const float*)d_in[0];
    float* out = (float*)d_out;
    float* out_idx = out;                              // B*NPOINT floats
    float* out_xyz = out + (size_t)BATCH * NPOINT;     // B*NPOINT*3 floats

    // Opt into >64KB dynamic LDS (runtime call, not captured by graphs).
    (void)hipFuncSetAttribute((const void*)fps_kernel,
                              hipFuncAttributeMaxDynamicSharedMemorySize,
                              SMEM_BYTES);

    fps_kernel<<<BATCH, NT, SMEM_BYTES, stream>>>(xyz, out_idx, out_xyz);
}